// Round 1
// baseline (176.118 us; speedup 1.0000x reference)
//
#include <hip/hip_runtime.h>
#include <math.h>

#define N_NODES 50000
#define N_EDGES 800000
#define DQ 32            // d-columns per block (quarter of 128)
#define KD 256           // inner dim (2*D)
#define W1S 260          // padded LDS stride (260*4B = 1040B, 16B aligned, spreads bank quads)
#define TILE_ROWS 16
#define N_TILES (N_NODES / TILE_ROWS)   // 3125 exact

// Stage 1: s[m] = sum_d W2[d] * sin( dot(x[m,:], W1[d,:]) + b1[d] )
// Each block owns a d-quarter (q = blockIdx&3) and grid-strides over 16-row tiles.
// Thread (g, dq): g = tid>>5 (8 row-groups x 2 rows), dq = tid&31 (d within quarter).
__global__ __launch_bounds__(256, 3) void stage1_kernel(
    const float* __restrict__ x, const float* __restrict__ W1,
    const float* __restrict__ b1, const float* __restrict__ W2,
    float* __restrict__ s)
{
    __shared__ float w1s[DQ * W1S];       // 33280 floats
    __shared__ float xs[TILE_ROWS * KD];  // 4096 floats  (total 49664 B -> 3 blocks/CU)

    const int tid = threadIdx.x;
    const int q = blockIdx.x & 3;

    // Stage W1 quarter into LDS (coalesced float4), once per block.
    const float4* w1g = (const float4*)(W1 + q * DQ * KD);
    for (int c = tid; c < DQ * (KD / 4); c += 256) {
        int dd = c >> 6, kc = c & 63;
        float4 v = w1g[c];
        *(float4*)&w1s[dd * W1S + kc * 4] = v;
    }

    const int dq = tid & 31;
    const int g  = tid >> 5;
    const float b1d = b1[q * DQ + dq];
    const float w2d = W2[q * DQ + dq];
    const float* wrow = &w1s[dq * W1S];

    for (int tile = blockIdx.x >> 2; tile < N_TILES; tile += (gridDim.x >> 2)) {
        const int m0 = tile * TILE_ROWS;
        __syncthreads();  // protect xs (and W1 staging on first iter)
        const float4* xg = (const float4*)(x + (size_t)m0 * KD);
        for (int c = tid; c < TILE_ROWS * (KD / 4); c += 256)
            ((float4*)xs)[c] = xg[c];
        __syncthreads();

        float acc0 = 0.f, acc1 = 0.f;
        const float* xr0 = &xs[(g * 2 + 0) * KD];
        const float* xr1 = &xs[(g * 2 + 1) * KD];
        #pragma unroll 8
        for (int kc = 0; kc < KD / 4; ++kc) {
            float4 w = *(const float4*)(wrow + kc * 4);   // per-lane LDS b128
            float4 a = *(const float4*)(xr0 + kc * 4);    // broadcast
            float4 b = *(const float4*)(xr1 + kc * 4);    // broadcast
            acc0 = fmaf(w.x, a.x, acc0); acc0 = fmaf(w.y, a.y, acc0);
            acc0 = fmaf(w.z, a.z, acc0); acc0 = fmaf(w.w, a.w, acc0);
            acc1 = fmaf(w.x, b.x, acc1); acc1 = fmaf(w.y, b.y, acc1);
            acc1 = fmaf(w.z, b.z, acc1); acc1 = fmaf(w.w, b.w, acc1);
        }

        float v0 = __sinf(acc0 + b1d) * w2d;
        float v1 = __sinf(acc1 + b1d) * w2d;
        // reduce over dq (32 lanes; XOR offsets <32 stay within each half-wave)
        #pragma unroll
        for (int off = 16; off; off >>= 1) {
            v0 += __shfl_xor(v0, off);
            v1 += __shfl_xor(v1, off);
        }
        if (dq == 0) {
            atomicAdd(&s[m0 + g * 2 + 0], v0);
            atomicAdd(&s[m0 + g * 2 + 1], v1);
        }
    }
}

// Stage 2: t[row[e]] += w[e] * s[col[e]]   (scalar SpMV, 1 atomic/edge)
__global__ void spmv_kernel(const int* __restrict__ erow, const int* __restrict__ ecol,
                            const float* __restrict__ ew, const float* __restrict__ s,
                            float* __restrict__ t)
{
    int e = blockIdx.x * 256 + threadIdx.x;
    if (e < N_EDGES) {
        atomicAdd(&t[erow[e]], ew[e] * s[ecol[e]]);
    }
}

// Stage 3: out += sum_n sin(t[n]+b2)^2  (block-reduced, one atomic per block)
__global__ void finish_kernel(const float* __restrict__ t, const float* __restrict__ b2,
                              float* __restrict__ out)
{
    int n = blockIdx.x * 256 + threadIdx.x;
    float bb = b2[0];
    float v = 0.f;
    if (n < N_NODES) { float o = __sinf(t[n] + bb); v = o * o; }
    #pragma unroll
    for (int off = 32; off; off >>= 1) v += __shfl_xor(v, off);
    __shared__ float partial[4];
    if ((threadIdx.x & 63) == 0) partial[threadIdx.x >> 6] = v;
    __syncthreads();
    if (threadIdx.x == 0)
        atomicAdd(out, partial[0] + partial[1] + partial[2] + partial[3]);
}

__global__ void sqrt_kernel(float* out) { out[0] = sqrtf(out[0]); }

extern "C" void kernel_launch(void* const* d_in, const int* in_sizes, int n_in,
                              void* d_out, int out_size, void* d_ws, size_t ws_size,
                              hipStream_t stream)
{
    const float* x   = (const float*)d_in[0];
    const float* W1  = (const float*)d_in[1];
    const float* b1  = (const float*)d_in[2];
    const float* W2  = (const float*)d_in[3];
    const float* b2  = (const float*)d_in[4];
    const int*   er  = (const int*)d_in[5];          // edge_index row part
    const int*   ec  = ((const int*)d_in[5]) + N_EDGES; // edge_index col part
    const float* ew  = (const float*)d_in[6];
    float* out = (float*)d_out;

    float* s_buf = (float*)d_ws;            // N_NODES floats
    float* t_buf = s_buf + N_NODES;         // N_NODES floats

    hipMemsetAsync(s_buf, 0, 2 * N_NODES * sizeof(float), stream);
    hipMemsetAsync(out, 0, sizeof(float), stream);

    stage1_kernel<<<1024, 256, 0, stream>>>(x, W1, b1, W2, s_buf);
    spmv_kernel<<<(N_EDGES + 255) / 256, 256, 0, stream>>>(er, ec, ew, s_buf, t_buf);
    finish_kernel<<<(N_NODES + 255) / 256, 256, 0, stream>>>(t_buf, b2, out);
    sqrt_kernel<<<1, 1, 0, stream>>>(out);
}

// Round 2
// 91.517 us; speedup vs baseline: 1.9244x; 1.9244x over previous
//
#include <hip/hip_runtime.h>
#include <math.h>

#define NN 50000
#define NE 800000
#define KD 256      // 2*D
#define DD 128
#define ROWS 32
#define STR 272     // padded LDS row stride in bf16 elems (544 B): 8 lanes per 4-bank group = b128 floor
#define NT ((NN + ROWS - 1) / ROWS)   // 1563 tiles
#define S1_GRID 256

typedef __bf16 bf16x4 __attribute__((ext_vector_type(4)));
typedef __bf16 bf16x8 __attribute__((ext_vector_type(8)));
typedef float f32x4 __attribute__((ext_vector_type(4)));

// Stage 1 (MFMA): s[m] = sum_d W2[d] * sin( (x @ W1^T)[m,d] + b1[d] )
// Persistent 256 blocks, 1/CU (104 KB LDS). Full d=128 per block -> x read once, s stored directly.
__global__ __launch_bounds__(256, 1) void stage1_kernel(
    const float* __restrict__ x, const float* __restrict__ W1,
    const float* __restrict__ b1, const float* __restrict__ W2,
    float* __restrict__ s)
{
    __shared__ __align__(16) __bf16 w1s[DD * STR];        // 69632 B
    __shared__ __align__(16) __bf16 xs[2][ROWS * STR];    // 34816 B
    __shared__ float sred[4][ROWS];                       // 512 B

    const int tid  = threadIdx.x;
    const int lane = tid & 63;
    const int w    = tid >> 6;      // wave id 0..3
    const int g    = lane >> 4;     // k-group 0..3
    const int li   = lane & 15;     // row/col within 16

    // Stage W1 (fp32 global -> bf16 LDS), once per block. Coalesced float4, conflict-free b64 writes.
    for (int c = tid; c < DD * (KD / 4); c += 256) {
        int r = c >> 6, kq = c & 63;
        float4 v = ((const float4*)W1)[c];
        bf16x4 h = { (__bf16)v.x, (__bf16)v.y, (__bf16)v.z, (__bf16)v.w };
        *(bf16x4*)&w1s[r * STR + kq * 4] = h;
    }

    const int d0 = w * 32 + li;               // wave owns d in [w*32, w*32+32)
    const float b1v0 = b1[d0], b1v1 = b1[d0 + 16];
    const float w2v0 = W2[d0], w2v1 = W2[d0 + 16];

    // Prologue: load first tile into registers (8 x float4 per thread = 32 rows x 256 f32 per block)
    float4 xr[8];
    int t = blockIdx.x;
    {
        const int m0 = t * ROWS;
        #pragma unroll
        for (int i = 0; i < 8; ++i) {
            int c = tid + i * 256;
            int r = c >> 6, kq = c & 63;
            if (m0 + r < NN) xr[i] = ((const float4*)x)[(size_t)(m0 + r) * 64 + kq];
        }
    }

    int buf = 0;
    while (t < NT) {
        const int m0 = t * ROWS;

        // Convert + write current tile into xs[buf] (consecutive lanes -> consecutive addrs, conflict-free)
        #pragma unroll
        for (int i = 0; i < 8; ++i) {
            int c = tid + i * 256;
            int r = c >> 6, kq = c & 63;
            bf16x4 h = { (__bf16)xr[i].x, (__bf16)xr[i].y, (__bf16)xr[i].z, (__bf16)xr[i].w };
            *(bf16x4*)&xs[buf][r * STR + kq * 4] = h;
        }
        __syncthreads();   // bar A: xs[buf] (and W1 on first iter) visible

        // Issue next tile's global loads now; they fly under the MFMA k-loop (T14 issue-early)
        const int tn = t + S1_GRID;
        if (tn < NT) {
            const int mn = tn * ROWS;
            #pragma unroll
            for (int i = 0; i < 8; ++i) {
                int c = tid + i * 256;
                int r = c >> 6, kq = c & 63;
                if (mn + r < NN) xr[i] = ((const float4*)x)[(size_t)(mn + r) * 64 + kq];
            }
        }

        // K-loop: 8 steps of 32. Per wave: 2 A frags (rows 0-15,16-31) x 2 B frags (d-tiles) -> 4 MFMA.
        // A and B loaded with the SAME (g,j)->k map (k = ks*32 + g*8 + j), so any HW k-order is correct.
        f32x4 acc[2][2] = {};
        #pragma unroll
        for (int ks = 0; ks < 8; ++ks) {
            const int ko = ks * 32 + g * 8;
            bf16x8 a0 = *(const bf16x8*)&xs[buf][li * STR + ko];
            bf16x8 a1 = *(const bf16x8*)&xs[buf][(li + 16) * STR + ko];
            bf16x8 b0 = *(const bf16x8*)&w1s[d0 * STR + ko];
            bf16x8 b1f = *(const bf16x8*)&w1s[(d0 + 16) * STR + ko];
            acc[0][0] = __builtin_amdgcn_mfma_f32_16x16x32_bf16(a0, b0,  acc[0][0], 0, 0, 0);
            acc[0][1] = __builtin_amdgcn_mfma_f32_16x16x32_bf16(a0, b1f, acc[0][1], 0, 0, 0);
            acc[1][0] = __builtin_amdgcn_mfma_f32_16x16x32_bf16(a1, b0,  acc[1][0], 0, 0, 0);
            acc[1][1] = __builtin_amdgcn_mfma_f32_16x16x32_bf16(a1, b1f, acc[1][1], 0, 0, 0);
        }

        // Epilogue: v = sin(acc + b1)*W2, reduce over d.
        // C/D layout (verified m89): col(d) = lane&15, row(m) = (lane>>4)*4 + reg.
        #pragma unroll
        for (int mt = 0; mt < 2; ++mt) {
            #pragma unroll
            for (int r = 0; r < 4; ++r) {
                float v = __sinf(acc[mt][0][r] + b1v0) * w2v0
                        + __sinf(acc[mt][1][r] + b1v1) * w2v1;
                v += __shfl_xor(v, 1); v += __shfl_xor(v, 2);
                v += __shfl_xor(v, 4); v += __shfl_xor(v, 8);
                if (li == 0) sred[w][mt * 16 + g * 4 + r] = v;
            }
        }
        __syncthreads();   // bar B: sred complete
        if (tid < ROWS) {
            int m = m0 + tid;
            if (m < NN) s[m] = sred[0][tid] + sred[1][tid] + sred[2][tid] + sred[3][tid];
        }
        buf ^= 1;
        t = tn;
    }
}

// Stage 2: t[row[e]] += w[e] * s[col[e]]   (scalar SpMV, 1 atomic/edge; s is L2-resident)
__global__ void spmv_kernel(const int* __restrict__ erow, const int* __restrict__ ecol,
                            const float* __restrict__ ew, const float* __restrict__ s,
                            float* __restrict__ t)
{
    int e = blockIdx.x * 256 + threadIdx.x;
    if (e < NE) {
        atomicAdd(&t[erow[e]], ew[e] * s[ecol[e]]);
    }
}

// Stage 3: out += sum_n sin(t[n]+b2)^2
__global__ void finish_kernel(const float* __restrict__ t, const float* __restrict__ b2,
                              float* __restrict__ out)
{
    int n = blockIdx.x * 256 + threadIdx.x;
    float bb = b2[0];
    float v = 0.f;
    if (n < NN) { float o = __sinf(t[n] + bb); v = o * o; }
    #pragma unroll
    for (int off = 32; off; off >>= 1) v += __shfl_xor(v, off);
    __shared__ float partial[4];
    if ((threadIdx.x & 63) == 0) partial[threadIdx.x >> 6] = v;
    __syncthreads();
    if (threadIdx.x == 0)
        atomicAdd(out, partial[0] + partial[1] + partial[2] + partial[3]);
}

__global__ void sqrt_kernel(float* out) { out[0] = sqrtf(out[0]); }

extern "C" void kernel_launch(void* const* d_in, const int* in_sizes, int n_in,
                              void* d_out, int out_size, void* d_ws, size_t ws_size,
                              hipStream_t stream)
{
    const float* x   = (const float*)d_in[0];
    const float* W1  = (const float*)d_in[1];
    const float* b1  = (const float*)d_in[2];
    const float* W2  = (const float*)d_in[3];
    const float* b2  = (const float*)d_in[4];
    const int*   er  = (const int*)d_in[5];              // edge_index[0]
    const int*   ec  = ((const int*)d_in[5]) + NE;       // edge_index[1]
    const float* ew  = (const float*)d_in[6];
    float* out = (float*)d_out;

    float* s_buf = (float*)d_ws;            // NN floats (written fully by stage1, no zeroing needed)
    float* t_buf = s_buf + NN;              // NN floats (atomic target, must be zeroed)

    hipMemsetAsync(t_buf, 0, NN * sizeof(float), stream);
    hipMemsetAsync(out, 0, sizeof(float), stream);

    stage1_kernel<<<S1_GRID, 256, 0, stream>>>(x, W1, b1, W2, s_buf);
    spmv_kernel<<<(NE + 255) / 256, 256, 0, stream>>>(er, ec, ew, s_buf, t_buf);
    finish_kernel<<<(NN + 255) / 256, 256, 0, stream>>>(t_buf, b2, out);
    sqrt_kernel<<<1, 1, 0, stream>>>(out);
}

// Round 3
// 87.622 us; speedup vs baseline: 2.0100x; 1.0445x over previous
//
#include <hip/hip_runtime.h>
#include <math.h>

#define NN 50000
#define NE 800000
#define KD 256      // 2*D
#define DD 128
#define ROWS 32
#define STR 264     // padded LDS stride (528 B = 132 dw ≡ 4 banks/row -> free 2-way on b128)
#define NT ((NN + ROWS - 1) / ROWS)   // 1563 tiles
#define S1_GRID 256
#define NCOPY 4
#define CSTRIDE 800000   // 50000 nodes * 16 floats (one 64B line per node per copy)

typedef __bf16 bf16x4 __attribute__((ext_vector_type(4)));
typedef __bf16 bf16x8 __attribute__((ext_vector_type(8)));
typedef float f32x4 __attribute__((ext_vector_type(4)));

// Stage 1 (MFMA): s[m] = sum_d W2[d] * sin( (x @ W1^T)[m,d] + b1[d] )
// Also zeroes the t accumulator array + out (fire-and-forget stores, hidden under latency).
__global__ __launch_bounds__(256, 1) void stage1_kernel(
    const float* __restrict__ x, const float* __restrict__ W1,
    const float* __restrict__ b1, const float* __restrict__ W2,
    float* __restrict__ s, float* __restrict__ tz, int tz_f4,
    float* __restrict__ out)
{
    __shared__ __align__(16) __bf16 w1s[DD * STR];        // 67584 B
    __shared__ __align__(16) __bf16 xs[2][ROWS * STR];    // 33792 B
    __shared__ float sred[4][ROWS];

    const int tid  = threadIdx.x;
    const int lane = tid & 63;
    const int w    = tid >> 6;
    const int g    = lane >> 4;
    const int li   = lane & 15;

    // Zero the atomic target array + out (streams out, no dependency until kernel end)
    for (int i = blockIdx.x * 256 + tid; i < tz_f4; i += S1_GRID * 256) {
        float4 z = {0.f, 0.f, 0.f, 0.f};
        ((float4*)tz)[i] = z;
    }
    if (blockIdx.x == 0 && tid == 0) out[0] = 0.f;

    // Stage W1 (fp32 -> bf16 LDS), once per block
    for (int c = tid; c < DD * (KD / 4); c += 256) {
        int r = c >> 6, kq = c & 63;
        float4 v = ((const float4*)W1)[c];
        bf16x4 h = { (__bf16)v.x, (__bf16)v.y, (__bf16)v.z, (__bf16)v.w };
        *(bf16x4*)&w1s[r * STR + kq * 4] = h;
    }

    const int d0 = w * 32 + li;
    const float b1v0 = b1[d0], b1v1 = b1[d0 + 16];
    const float w2v0 = W2[d0], w2v1 = W2[d0 + 16];

    float4 xrA[8] = {}, xrB[8] = {};
    int t = blockIdx.x;
    {   // prologue: first tile into xrA
        const int m0 = t * ROWS;
        #pragma unroll
        for (int i = 0; i < 8; ++i) {
            int c = tid + i * 256;
            int r = c >> 6, kq = c & 63;
            if (m0 + r < NN) xrA[i] = ((const float4*)x)[(size_t)(m0 + r) * 64 + kq];
        }
    }

    int buf = 0;
    while (t < NT) {
        const int m0 = t * ROWS;
        const int tn = t + S1_GRID;

        // Issue NEXT tile's loads first — a full iteration (~write+kloop+epilogue) flies before use
        if (tn < NT) {
            const int mn = tn * ROWS;
            #pragma unroll
            for (int i = 0; i < 8; ++i) {
                int c = tid + i * 256;
                int r = c >> 6, kq = c & 63;
                if (mn + r < NN) xrB[i] = ((const float4*)x)[(size_t)(mn + r) * 64 + kq];
            }
        }

        // Convert + write CURRENT tile (waits only on xrA's loads: vmcnt(8))
        #pragma unroll
        for (int i = 0; i < 8; ++i) {
            int c = tid + i * 256;
            int r = c >> 6, kq = c & 63;
            bf16x4 h = { (__bf16)xrA[i].x, (__bf16)xrA[i].y, (__bf16)xrA[i].z, (__bf16)xrA[i].w };
            *(bf16x4*)&xs[buf][r * STR + kq * 4] = h;
        }
        __syncthreads();   // bar A: xs[buf] (and W1 on first iter) visible

        // K-loop: 8 steps of 32; A and B use the same (g,j)->k bijection
        f32x4 acc[2][2] = {};
        #pragma unroll
        for (int ks = 0; ks < 8; ++ks) {
            const int ko = ks * 32 + g * 8;
            bf16x8 a0  = *(const bf16x8*)&xs[buf][li * STR + ko];
            bf16x8 a1  = *(const bf16x8*)&xs[buf][(li + 16) * STR + ko];
            bf16x8 b0  = *(const bf16x8*)&w1s[d0 * STR + ko];
            bf16x8 b1f = *(const bf16x8*)&w1s[(d0 + 16) * STR + ko];
            acc[0][0] = __builtin_amdgcn_mfma_f32_16x16x32_bf16(a0, b0,  acc[0][0], 0, 0, 0);
            acc[0][1] = __builtin_amdgcn_mfma_f32_16x16x32_bf16(a0, b1f, acc[0][1], 0, 0, 0);
            acc[1][0] = __builtin_amdgcn_mfma_f32_16x16x32_bf16(a1, b0,  acc[1][0], 0, 0, 0);
            acc[1][1] = __builtin_amdgcn_mfma_f32_16x16x32_bf16(a1, b1f, acc[1][1], 0, 0, 0);
        }

        // Epilogue: v = sin(acc+b1)*W2, reduce over d (C/D layout: col=lane&15, row=(lane>>4)*4+reg)
        #pragma unroll
        for (int mt = 0; mt < 2; ++mt) {
            #pragma unroll
            for (int r = 0; r < 4; ++r) {
                float v = __sinf(acc[mt][0][r] + b1v0) * w2v0
                        + __sinf(acc[mt][1][r] + b1v1) * w2v1;
                v += __shfl_xor(v, 1); v += __shfl_xor(v, 2);
                v += __shfl_xor(v, 4); v += __shfl_xor(v, 8);
                if (li == 0) sred[w][mt * 16 + g * 4 + r] = v;
            }
        }
        __syncthreads();   // bar B: sred complete (also write-hazard guard for xs)
        if (tid < ROWS) {
            int m = m0 + tid;
            if (m < NN) s[m] = sred[0][tid] + sred[1][tid] + sred[2][tid] + sred[3][tid];
        }
        #pragma unroll
        for (int i = 0; i < 8; ++i) xrA[i] = xrB[i];
        buf ^= 1;
        t = tn;
    }
}

// Stage 2: scatter t[(copy j)][row]. Padded layout: addr = j*cstride + (r << padshift).
// 4 edges/thread via int4/float4 loads; each edge of the quad goes to a different copy.
__global__ void spmv_kernel(const int* __restrict__ erow, const int* __restrict__ ecol,
                            const float* __restrict__ ew, const float* __restrict__ s,
                            float* __restrict__ t, int cstride, int padshift)
{
    int i = blockIdx.x * 256 + threadIdx.x;
    if (i >= NE / 4) return;
    int4   r4 = ((const int4*)erow)[i];
    int4   c4 = ((const int4*)ecol)[i];
    float4 w4 = ((const float4*)ew)[i];
    atomicAdd(&t[(size_t)0 * cstride + ((size_t)r4.x << padshift)], w4.x * s[c4.x]);
    atomicAdd(&t[(size_t)1 * cstride + ((size_t)r4.y << padshift)], w4.y * s[c4.y]);
    atomicAdd(&t[(size_t)2 * cstride + ((size_t)r4.z << padshift)], w4.z * s[c4.z]);
    atomicAdd(&t[(size_t)3 * cstride + ((size_t)r4.w << padshift)], w4.w * s[c4.w]);
}

// Stage 3: out += sum_n sin( sum_copies t[...] + b2 )^2
__global__ void finish_kernel(const float* __restrict__ t, const float* __restrict__ b2,
                              float* __restrict__ out, int cstride, int padshift, int ncopies)
{
    int n = blockIdx.x * 256 + threadIdx.x;
    float bb = b2[0];
    float v = 0.f;
    if (n < NN) {
        float a = 0.f;
        for (int j = 0; j < ncopies; ++j)
            a += t[(size_t)j * cstride + ((size_t)n << padshift)];
        float o = __sinf(a + bb);
        v = o * o;
    }
    #pragma unroll
    for (int off = 32; off; off >>= 1) v += __shfl_xor(v, off);
    __shared__ float partial[4];
    if ((threadIdx.x & 63) == 0) partial[threadIdx.x >> 6] = v;
    __syncthreads();
    if (threadIdx.x == 0)
        atomicAdd(out, partial[0] + partial[1] + partial[2] + partial[3]);
}

__global__ void sqrt_kernel(float* out) { out[0] = sqrtf(out[0]); }

extern "C" void kernel_launch(void* const* d_in, const int* in_sizes, int n_in,
                              void* d_out, int out_size, void* d_ws, size_t ws_size,
                              hipStream_t stream)
{
    const float* x   = (const float*)d_in[0];
    const float* W1  = (const float*)d_in[1];
    const float* b1  = (const float*)d_in[2];
    const float* W2  = (const float*)d_in[3];
    const float* b2  = (const float*)d_in[4];
    const int*   er  = (const int*)d_in[5];
    const int*   ec  = ((const int*)d_in[5]) + NE;
    const float* ew  = (const float*)d_in[6];
    float* out = (float*)d_out;

    float* s_buf = (float*)d_ws;            // 50176 floats (aligned region)
    float* t_buf = s_buf + 50176;

    // Padded+replicated layout if workspace allows, else dense fallback
    size_t need = (size_t)(50176 + NCOPY * CSTRIDE) * sizeof(float);
    int cstride, padshift, ncopies, tz_f4;
    if (ws_size >= need) { cstride = CSTRIDE; padshift = 4; ncopies = NCOPY; tz_f4 = NCOPY * CSTRIDE / 4; }
    else                 { cstride = 0;       padshift = 0; ncopies = 1;     tz_f4 = (NN + 3) / 4; }

    stage1_kernel<<<S1_GRID, 256, 0, stream>>>(x, W1, b1, W2, s_buf, t_buf, tz_f4, out);
    spmv_kernel<<<(NE / 4 + 255) / 256, 256, 0, stream>>>(er, ec, ew, s_buf, t_buf, cstride, padshift);
    finish_kernel<<<(NN + 255) / 256, 256, 0, stream>>>(t_buf, b2, out, cstride, padshift, ncopies);
    sqrt_kernel<<<1, 1, 0, stream>>>(out);
}

// Round 4
// 53.188 us; speedup vs baseline: 3.3112x; 1.6474x over previous
//
#include <hip/hip_runtime.h>
#include <math.h>

#define NN 50000
#define NE 800000
#define KD 256      // 2*D
#define DD 128
#define ROWS 32
#define STR 264     // padded LDS stride (528 B): free 2-way on b128
#define NT ((NN + ROWS - 1) / ROWS)   // 1563 tiles
#define S1_GRID 256

// SpMV privatization geometry
#define EC 64        // edge chunks
#define NR 4         // node ranges
#define RNG 12500    // nodes per range (NN/NR)
#define QPC 3125     // int4-quads per chunk (NE/4/EC)

typedef __bf16 bf16x4 __attribute__((ext_vector_type(4)));
typedef __bf16 bf16x8 __attribute__((ext_vector_type(8)));
typedef float f32x4 __attribute__((ext_vector_type(4)));

// Stage 1 (MFMA): s[m] = sum_d W2[d] * sin( (x @ W1^T)[m,d] + b1[d] ); also zeroes out[0].
__global__ __launch_bounds__(256, 1) void stage1_kernel(
    const float* __restrict__ x, const float* __restrict__ W1,
    const float* __restrict__ b1, const float* __restrict__ W2,
    float* __restrict__ s, float* __restrict__ out)
{
    __shared__ __align__(16) __bf16 w1s[DD * STR];
    __shared__ __align__(16) __bf16 xs[2][ROWS * STR];
    __shared__ float sred[4][ROWS];

    const int tid  = threadIdx.x;
    const int lane = tid & 63;
    const int w    = tid >> 6;
    const int g    = lane >> 4;
    const int li   = lane & 15;

    if (blockIdx.x == 0 && tid == 0) out[0] = 0.f;

    // Stage W1 (fp32 -> bf16 LDS), once per block
    for (int c = tid; c < DD * (KD / 4); c += 256) {
        int r = c >> 6, kq = c & 63;
        float4 v = ((const float4*)W1)[c];
        bf16x4 h = { (__bf16)v.x, (__bf16)v.y, (__bf16)v.z, (__bf16)v.w };
        *(bf16x4*)&w1s[r * STR + kq * 4] = h;
    }

    const int d0 = w * 32 + li;
    const float b1v0 = b1[d0], b1v1 = b1[d0 + 16];
    const float w2v0 = W2[d0], w2v1 = W2[d0 + 16];

    float4 xrA[8] = {}, xrB[8] = {};
    int t = blockIdx.x;
    {
        const int m0 = t * ROWS;
        #pragma unroll
        for (int i = 0; i < 8; ++i) {
            int c = tid + i * 256;
            int r = c >> 6, kq = c & 63;
            if (m0 + r < NN) xrA[i] = ((const float4*)x)[(size_t)(m0 + r) * 64 + kq];
        }
    }

    int buf = 0;
    while (t < NT) {
        const int m0 = t * ROWS;
        const int tn = t + S1_GRID;

        // Issue NEXT tile's loads a full iteration ahead
        if (tn < NT) {
            const int mn = tn * ROWS;
            #pragma unroll
            for (int i = 0; i < 8; ++i) {
                int c = tid + i * 256;
                int r = c >> 6, kq = c & 63;
                if (mn + r < NN) xrB[i] = ((const float4*)x)[(size_t)(mn + r) * 64 + kq];
            }
        }

        // Convert + write CURRENT tile
        #pragma unroll
        for (int i = 0; i < 8; ++i) {
            int c = tid + i * 256;
            int r = c >> 6, kq = c & 63;
            bf16x4 h = { (__bf16)xrA[i].x, (__bf16)xrA[i].y, (__bf16)xrA[i].z, (__bf16)xrA[i].w };
            *(bf16x4*)&xs[buf][r * STR + kq * 4] = h;
        }
        __syncthreads();

        f32x4 acc[2][2] = {};
        #pragma unroll
        for (int ks = 0; ks < 8; ++ks) {
            const int ko = ks * 32 + g * 8;
            bf16x8 a0  = *(const bf16x8*)&xs[buf][li * STR + ko];
            bf16x8 a1  = *(const bf16x8*)&xs[buf][(li + 16) * STR + ko];
            bf16x8 b0  = *(const bf16x8*)&w1s[d0 * STR + ko];
            bf16x8 b1f = *(const bf16x8*)&w1s[(d0 + 16) * STR + ko];
            acc[0][0] = __builtin_amdgcn_mfma_f32_16x16x32_bf16(a0, b0,  acc[0][0], 0, 0, 0);
            acc[0][1] = __builtin_amdgcn_mfma_f32_16x16x32_bf16(a0, b1f, acc[0][1], 0, 0, 0);
            acc[1][0] = __builtin_amdgcn_mfma_f32_16x16x32_bf16(a1, b0,  acc[1][0], 0, 0, 0);
            acc[1][1] = __builtin_amdgcn_mfma_f32_16x16x32_bf16(a1, b1f, acc[1][1], 0, 0, 0);
        }

        #pragma unroll
        for (int mt = 0; mt < 2; ++mt) {
            #pragma unroll
            for (int r = 0; r < 4; ++r) {
                float v = __sinf(acc[mt][0][r] + b1v0) * w2v0
                        + __sinf(acc[mt][1][r] + b1v1) * w2v1;
                v += __shfl_xor(v, 1); v += __shfl_xor(v, 2);
                v += __shfl_xor(v, 4); v += __shfl_xor(v, 8);
                if (li == 0) sred[w][mt * 16 + g * 4 + r] = v;
            }
        }
        __syncthreads();
        if (tid < ROWS) {
            int m = m0 + tid;
            if (m < NN) s[m] = sred[0][tid] + sred[1][tid] + sred[2][tid] + sred[3][tid];
        }
        #pragma unroll
        for (int i = 0; i < 8; ++i) xrA[i] = xrB[i];
        buf ^= 1;
        t = tn;
    }
}

// Stage 2 (LDS-privatized, atomic-free at device scope):
// block (nr, ecid): scan chunk ecid, accumulate rows in [nr*RNG, (nr+1)*RNG) into LDS,
// then write the partial range to P[ecid][nr*RNG .. +RNG). ecid = blockIdx&63 so the
// 4 blocks sharing a chunk land on the same XCD (stride 64 = 0 mod 8).
__global__ __launch_bounds__(1024, 1) void spmv_lds_kernel(
    const int* __restrict__ erow, const int* __restrict__ ecol,
    const float* __restrict__ ew, const float* __restrict__ s,
    float* __restrict__ P)
{
    __shared__ float lt[RNG];
    const int tid  = threadIdx.x;
    const int ecid = blockIdx.x & 63;
    const int nr   = blockIdx.x >> 6;
    const int base = nr * RNG;

    for (int i = tid; i < RNG; i += 1024) lt[i] = 0.f;
    __syncthreads();

    const int4*   r4p = (const int4*)erow;
    const int4*   c4p = (const int4*)ecol;
    const float4* w4p = (const float4*)ew;
    for (int q = tid; q < QPC; q += 1024) {
        int i = ecid * QPC + q;
        int4   r4 = r4p[i];
        int4   c4 = c4p[i];
        float4 w4 = w4p[i];
        unsigned a;
        a = (unsigned)(r4.x - base); if (a < RNG) atomicAdd(&lt[a], w4.x * s[c4.x]);
        a = (unsigned)(r4.y - base); if (a < RNG) atomicAdd(&lt[a], w4.y * s[c4.y]);
        a = (unsigned)(r4.z - base); if (a < RNG) atomicAdd(&lt[a], w4.z * s[c4.z]);
        a = (unsigned)(r4.w - base); if (a < RNG) atomicAdd(&lt[a], w4.w * s[c4.w]);
    }
    __syncthreads();

    float4*       dst = (float4*)(P + (size_t)ecid * NN + base);
    const float4* src = (const float4*)lt;
    for (int j = tid; j < RNG / 4; j += 1024) dst[j] = src[j];
}

// Stage 3 (main path): out += sum_n sin( sum_ec P[ec][n] + b2 )^2
__global__ void finish_lds_kernel(const float* __restrict__ P, const float* __restrict__ b2,
                                  float* __restrict__ out)
{
    int n = blockIdx.x * 256 + threadIdx.x;
    float v = 0.f;
    if (n < NN) {
        float a = 0.f;
        #pragma unroll 8
        for (int ec = 0; ec < EC; ++ec) a += P[(size_t)ec * NN + n];
        float o = __sinf(a + b2[0]);
        v = o * o;
    }
    #pragma unroll
    for (int off = 32; off; off >>= 1) v += __shfl_xor(v, off);
    __shared__ float partial[4];
    if ((threadIdx.x & 63) == 0) partial[threadIdx.x >> 6] = v;
    __syncthreads();
    if (threadIdx.x == 0)
        atomicAdd(out, partial[0] + partial[1] + partial[2] + partial[3]);
}

// ---- Fallback path (small workspace): dense atomic SpMV ----
__global__ void spmv_fallback_kernel(const int* __restrict__ erow, const int* __restrict__ ecol,
                                     const float* __restrict__ ew, const float* __restrict__ s,
                                     float* __restrict__ t)
{
    int i = blockIdx.x * 256 + threadIdx.x;
    if (i >= NE / 4) return;
    int4   r4 = ((const int4*)erow)[i];
    int4   c4 = ((const int4*)ecol)[i];
    float4 w4 = ((const float4*)ew)[i];
    atomicAdd(&t[r4.x], w4.x * s[c4.x]);
    atomicAdd(&t[r4.y], w4.y * s[c4.y]);
    atomicAdd(&t[r4.z], w4.z * s[c4.z]);
    atomicAdd(&t[r4.w], w4.w * s[c4.w]);
}

__global__ void finish_fallback_kernel(const float* __restrict__ t, const float* __restrict__ b2,
                                       float* __restrict__ out)
{
    int n = blockIdx.x * 256 + threadIdx.x;
    float v = 0.f;
    if (n < NN) { float o = __sinf(t[n] + b2[0]); v = o * o; }
    #pragma unroll
    for (int off = 32; off; off >>= 1) v += __shfl_xor(v, off);
    __shared__ float partial[4];
    if ((threadIdx.x & 63) == 0) partial[threadIdx.x >> 6] = v;
    __syncthreads();
    if (threadIdx.x == 0)
        atomicAdd(out, partial[0] + partial[1] + partial[2] + partial[3]);
}

__global__ void sqrt_kernel(float* out) { out[0] = sqrtf(out[0]); }

extern "C" void kernel_launch(void* const* d_in, const int* in_sizes, int n_in,
                              void* d_out, int out_size, void* d_ws, size_t ws_size,
                              hipStream_t stream)
{
    const float* x   = (const float*)d_in[0];
    const float* W1  = (const float*)d_in[1];
    const float* b1  = (const float*)d_in[2];
    const float* W2  = (const float*)d_in[3];
    const float* b2  = (const float*)d_in[4];
    const int*   er  = (const int*)d_in[5];
    const int*   ec  = ((const int*)d_in[5]) + NE;
    const float* ew  = (const float*)d_in[6];
    float* out = (float*)d_out;

    float* s_buf = (float*)d_ws;            // 50176 floats
    float* P     = s_buf + 50176;           // EC*NN floats (main) or NN floats t (fallback)

    const size_t need = (size_t)(50176 + (size_t)EC * NN) * sizeof(float);

    stage1_kernel<<<S1_GRID, 256, 0, stream>>>(x, W1, b1, W2, s_buf, out);

    if (ws_size >= need) {
        spmv_lds_kernel<<<NR * EC, 1024, 0, stream>>>(er, ec, ew, s_buf, P);
        finish_lds_kernel<<<(NN + 255) / 256, 256, 0, stream>>>(P, b2, out);
    } else {
        hipMemsetAsync(P, 0, NN * sizeof(float), stream);
        spmv_fallback_kernel<<<(NE / 4 + 255) / 256, 256, 0, stream>>>(er, ec, ew, s_buf, P);
        finish_fallback_kernel<<<(NN + 255) / 256, 256, 0, stream>>>(P, b2, out);
    }
    sqrt_kernel<<<1, 1, 0, stream>>>(out);
}

// Round 5
// 47.998 us; speedup vs baseline: 3.6693x; 1.1081x over previous
//
#include <hip/hip_runtime.h>
#include <math.h>

#define NN 50000
#define NE 800000
#define KD 256      // 2*D
#define DD 128
#define ROWS 32
#define STR 264     // LDS row stride (bf16 elems)
#define NT ((NN + ROWS - 1) / ROWS)   // 1563

// SpMV privatization geometry
#define EC 64
#define NR 4
#define RNG 12500
#define QPC 3125

// workspace layout (floats)
#define S_OFF   0
#define P_OFF   50176
#define CNT_OFF (P_OFF + EC * NN)          // 3250176
#define W1P_OFF (CNT_OFF + 16)             // 3250192 (16B-aligned)
#define WS_NEED ((size_t)(W1P_OFF + DD * KD / 2 + 16) * 4)

typedef __bf16 bf16x4 __attribute__((ext_vector_type(4)));
typedef __bf16 bf16x8 __attribute__((ext_vector_type(8)));
typedef float f32x4 __attribute__((ext_vector_type(4)));

// Prep: W1 f32 [128][256] -> bf16 row-major [128][256] (one-time, L2-resident after)
__global__ void prep_w1_kernel(const float* __restrict__ W1, __bf16* __restrict__ W1p)
{
    int i = blockIdx.x * 256 + threadIdx.x;   // 8192 float4s
    if (i < DD * KD / 4) {
        float4 v = ((const float4*)W1)[i];
        bf16x4 h = { (__bf16)v.x, (__bf16)v.y, (__bf16)v.z, (__bf16)v.w };
        *(bf16x4*)&W1p[i * 4] = h;
    }
}

// Stage 1 (MFMA, high-occupancy): one 32-row tile per block, W1 frags in VGPRs,
// LDS only for the x tile (17 KB) -> 3 blocks/CU (VGPR-capped), latency hidden by TLP.
__global__ __launch_bounds__(256, 3) void stage1_kernel(
    const float* __restrict__ x, const __bf16* __restrict__ W1p,
    const float* __restrict__ b1, const float* __restrict__ W2,
    float* __restrict__ s, float* __restrict__ out, unsigned* __restrict__ counter)
{
    __shared__ __align__(16) __bf16 xs[ROWS * STR];   // 16896 B
    __shared__ float sred[4][ROWS];

    const int tid  = threadIdx.x;
    const int lane = tid & 63;
    const int w    = tid >> 6;
    const int g    = lane >> 4;
    const int li   = lane & 15;
    const int m0   = blockIdx.x * ROWS;

    if (blockIdx.x == 0 && tid == 0) { out[0] = 0.f; counter[0] = 0u; }

    // Issue x tile loads (coalesced float4; clamp rows so no undefined regs)
    float4 xr[8];
    #pragma unroll
    for (int i = 0; i < 8; ++i) {
        int c = tid + i * 256;
        int r = c >> 6, kq = c & 63;
        int rr = m0 + r; rr = rr < NN ? rr : NN - 1;
        xr[i] = ((const float4*)x)[(size_t)rr * 64 + kq];
    }

    // B fragments from prepped bf16 W1 (L2-hit, 16 x 16B per lane).
    // Same (g,j)->k bijection as the A-side LDS reads: k = ks*32 + g*8 + j.
    const int d0 = w * 32 + li;
    bf16x8 bw0[8], bw1[8];
    #pragma unroll
    for (int ks = 0; ks < 8; ++ks) {
        bw0[ks] = *(const bf16x8*)&W1p[d0 * KD + ks * 32 + g * 8];
        bw1[ks] = *(const bf16x8*)&W1p[(d0 + 16) * KD + ks * 32 + g * 8];
    }
    const float b1v0 = b1[d0], b1v1 = b1[d0 + 16];
    const float w2v0 = W2[d0], w2v1 = W2[d0 + 16];

    // Convert + stage x tile to LDS
    #pragma unroll
    for (int i = 0; i < 8; ++i) {
        int c = tid + i * 256;
        int r = c >> 6, kq = c & 63;
        bf16x4 h = { (__bf16)xr[i].x, (__bf16)xr[i].y, (__bf16)xr[i].z, (__bf16)xr[i].w };
        *(bf16x4*)&xs[r * STR + kq * 4] = h;
    }
    __syncthreads();

    f32x4 acc[2][2] = {};
    #pragma unroll
    for (int ks = 0; ks < 8; ++ks) {
        const int ko = ks * 32 + g * 8;
        bf16x8 a0 = *(const bf16x8*)&xs[li * STR + ko];
        bf16x8 a1 = *(const bf16x8*)&xs[(li + 16) * STR + ko];
        acc[0][0] = __builtin_amdgcn_mfma_f32_16x16x32_bf16(a0, bw0[ks], acc[0][0], 0, 0, 0);
        acc[0][1] = __builtin_amdgcn_mfma_f32_16x16x32_bf16(a0, bw1[ks], acc[0][1], 0, 0, 0);
        acc[1][0] = __builtin_amdgcn_mfma_f32_16x16x32_bf16(a1, bw0[ks], acc[1][0], 0, 0, 0);
        acc[1][1] = __builtin_amdgcn_mfma_f32_16x16x32_bf16(a1, bw1[ks], acc[1][1], 0, 0, 0);
    }

    // Epilogue: v = sin(acc+b1)*W2, reduce over d (C/D: col=lane&15, row=(lane>>4)*4+reg)
    #pragma unroll
    for (int mt = 0; mt < 2; ++mt) {
        #pragma unroll
        for (int r = 0; r < 4; ++r) {
            float v = __sinf(acc[mt][0][r] + b1v0) * w2v0
                    + __sinf(acc[mt][1][r] + b1v1) * w2v1;
            v += __shfl_xor(v, 1); v += __shfl_xor(v, 2);
            v += __shfl_xor(v, 4); v += __shfl_xor(v, 8);
            if (li == 0) sred[w][mt * 16 + g * 4 + r] = v;
        }
    }
    __syncthreads();
    if (tid < ROWS) {
        int m = m0 + tid;
        if (m < NN) s[m] = sred[0][tid] + sred[1][tid] + sred[2][tid] + sred[3][tid];
    }
}

// Stage 2 (LDS-privatized, no device atomics): block (nr, ecid) scans chunk ecid,
// accumulates rows in its range into LDS, writes partial range to P[ecid][...].
__global__ __launch_bounds__(1024, 1) void spmv_lds_kernel(
    const int* __restrict__ erow, const int* __restrict__ ecol,
    const float* __restrict__ ew, const float* __restrict__ s,
    float* __restrict__ P)
{
    __shared__ float lt[RNG];
    const int tid  = threadIdx.x;
    const int ecid = blockIdx.x & 63;
    const int nr   = blockIdx.x >> 6;
    const int base = nr * RNG;

    for (int i = tid; i < RNG; i += 1024) lt[i] = 0.f;
    __syncthreads();

    const int4*   r4p = (const int4*)erow;
    const int4*   c4p = (const int4*)ecol;
    const float4* w4p = (const float4*)ew;
    for (int q = tid; q < QPC; q += 1024) {
        int i = ecid * QPC + q;
        int4   r4 = r4p[i];
        int4   c4 = c4p[i];
        float4 w4 = w4p[i];
        unsigned a;
        a = (unsigned)(r4.x - base); if (a < RNG) atomicAdd(&lt[a], w4.x * s[c4.x]);
        a = (unsigned)(r4.y - base); if (a < RNG) atomicAdd(&lt[a], w4.y * s[c4.y]);
        a = (unsigned)(r4.z - base); if (a < RNG) atomicAdd(&lt[a], w4.z * s[c4.z]);
        a = (unsigned)(r4.w - base); if (a < RNG) atomicAdd(&lt[a], w4.w * s[c4.w]);
    }
    __syncthreads();

    float4*       dst = (float4*)(P + (size_t)ecid * NN + base);
    const float4* src = (const float4*)lt;
    for (int j = tid; j < RNG / 4; j += 1024) dst[j] = src[j];
}

// Stage 3: out += sum_n sin(sum_ec P[ec][n] + b2)^2 ; last block applies sqrt.
__global__ void finish_lds_kernel(const float* __restrict__ P, const float* __restrict__ b2,
                                  float* __restrict__ out, unsigned* __restrict__ counter,
                                  int nblocks)
{
    int n = blockIdx.x * 256 + threadIdx.x;
    float v = 0.f;
    if (n < NN) {
        float a = 0.f;
        #pragma unroll 8
        for (int ec = 0; ec < EC; ++ec) a += P[(size_t)ec * NN + n];
        float o = __sinf(a + b2[0]);
        v = o * o;
    }
    #pragma unroll
    for (int off = 32; off; off >>= 1) v += __shfl_xor(v, off);
    __shared__ float partial[4];
    if ((threadIdx.x & 63) == 0) partial[threadIdx.x >> 6] = v;
    __syncthreads();
    if (threadIdx.x == 0) {
        atomicAdd(out, partial[0] + partial[1] + partial[2] + partial[3]);
        __threadfence();
        unsigned old = atomicAdd(counter, 1u);
        if (old == (unsigned)(nblocks - 1)) {
            float tot = atomicAdd(out, 0.f);   // atomic read: all prior adds visible
            out[0] = sqrtf(tot);
        }
    }
}

// ---- Fallback path (small workspace): dense atomic SpMV ----
__global__ void spmv_fallback_kernel(const int* __restrict__ erow, const int* __restrict__ ecol,
                                     const float* __restrict__ ew, const float* __restrict__ s,
                                     float* __restrict__ t)
{
    int i = blockIdx.x * 256 + threadIdx.x;
    if (i >= NE / 4) return;
    int4   r4 = ((const int4*)erow)[i];
    int4   c4 = ((const int4*)ecol)[i];
    float4 w4 = ((const float4*)ew)[i];
    atomicAdd(&t[r4.x], w4.x * s[c4.x]);
    atomicAdd(&t[r4.y], w4.y * s[c4.y]);
    atomicAdd(&t[r4.z], w4.z * s[c4.z]);
    atomicAdd(&t[r4.w], w4.w * s[c4.w]);
}

__global__ void finish_fallback_kernel(const float* __restrict__ t, const float* __restrict__ b2,
                                       float* __restrict__ out)
{
    int n = blockIdx.x * 256 + threadIdx.x;
    float v = 0.f;
    if (n < NN) { float o = __sinf(t[n] + b2[0]); v = o * o; }
    #pragma unroll
    for (int off = 32; off; off >>= 1) v += __shfl_xor(v, off);
    __shared__ float partial[4];
    if ((threadIdx.x & 63) == 0) partial[threadIdx.x >> 6] = v;
    __syncthreads();
    if (threadIdx.x == 0)
        atomicAdd(out, partial[0] + partial[1] + partial[2] + partial[3]);
}

__global__ void sqrt_kernel(float* out) { out[0] = sqrtf(out[0]); }

// Fallback stage1 prologue zeroing (fallback only)
__global__ void zero_kernel(float* t, float* out)
{
    int i = blockIdx.x * 256 + threadIdx.x;
    if (i < NN) t[i] = 0.f;
    if (i == 0) out[0] = 0.f;
}

extern "C" void kernel_launch(void* const* d_in, const int* in_sizes, int n_in,
                              void* d_out, int out_size, void* d_ws, size_t ws_size,
                              hipStream_t stream)
{
    const float* x   = (const float*)d_in[0];
    const float* W1  = (const float*)d_in[1];
    const float* b1  = (const float*)d_in[2];
    const float* W2  = (const float*)d_in[3];
    const float* b2  = (const float*)d_in[4];
    const int*   er  = (const int*)d_in[5];
    const int*   ec  = ((const int*)d_in[5]) + NE;
    const float* ew  = (const float*)d_in[6];
    float* out = (float*)d_out;

    float*    ws    = (float*)d_ws;
    float*    s_buf = ws + S_OFF;
    float*    P     = ws + P_OFF;
    unsigned* cnt   = (unsigned*)(ws + CNT_OFF);
    __bf16*   W1p   = (__bf16*)(ws + W1P_OFF);

    if (ws_size >= WS_NEED) {
        prep_w1_kernel<<<32, 256, 0, stream>>>(W1, W1p);
        stage1_kernel<<<NT, 256, 0, stream>>>(x, W1p, b1, W2, s_buf, out, cnt);
        spmv_lds_kernel<<<NR * EC, 1024, 0, stream>>>(er, ec, ew, s_buf, P);
        int fb = (NN + 255) / 256;
        finish_lds_kernel<<<fb, 256, 0, stream>>>(P, b2, out, cnt, fb);
    } else {
        // Dense-atomic fallback (needs only ~400 KB of ws)
        prep_w1_kernel<<<32, 256, 0, stream>>>(W1, (__bf16*)(ws + 50176 + NN));
        zero_kernel<<<(NN + 255) / 256, 256, 0, stream>>>(ws + 50176, out);
        stage1_kernel<<<NT, 256, 0, stream>>>(x, (const __bf16*)(ws + 50176 + NN), b1, W2,
                                              s_buf, out, (unsigned*)(ws + 50176 + NN + DD * KD / 2));
        spmv_fallback_kernel<<<(NE / 4 + 255) / 256, 256, 0, stream>>>(er, ec, ew, s_buf, ws + 50176);
        finish_fallback_kernel<<<(NN + 255) / 256, 256, 0, stream>>>(ws + 50176, b2, out);
        sqrt_kernel<<<1, 1, 0, stream>>>(out);
    }
}

// Round 6
// 41.358 us; speedup vs baseline: 4.2584x; 1.1605x over previous
//
#include <hip/hip_runtime.h>
#include <math.h>

#define NN 50000
#define NE 800000
#define KD 256      // 2*D
#define DD 128
#define ROWS 32
#define STR 264     // LDS row stride (bf16 elems)
#define NT ((NN + ROWS - 1) / ROWS)   // 1563

// SpMV privatization geometry
#define EC 64
#define NR 4
#define RNG 12500
#define QPC 3125

// workspace layout (floats)
#define S_OFF   0
#define P_OFF   50176
#define CNT_OFF (P_OFF + EC * NN)          // 3250176
#define W1P_OFF (CNT_OFF + 16)             // 3250192 (16B-aligned)
#define WS_NEED ((size_t)(W1P_OFF + DD * KD / 2 + 16) * 4)

typedef __bf16 bf16x4 __attribute__((ext_vector_type(4)));
typedef __bf16 bf16x8 __attribute__((ext_vector_type(8)));
typedef float f32x4 __attribute__((ext_vector_type(4)));

// Prep: W1 f32 [128][256] -> FRAGMENT-MAJOR bf16:
//   W1p[ ((dt*8 + ks)*64 + g*16 + li)*8 + j ] = W1[ (dt*16+li)*256 + ks*32 + g*8 + j ]
// so a wave's B-frag for (d-tile dt, k-step ks) is one contiguous 1 KB segment
// (lane = g*16+li reads its own 16 B chunk, fully coalesced).
__global__ void prep_w1_kernel(const float* __restrict__ W1, __bf16* __restrict__ W1p)
{
    int i = blockIdx.x * 256 + threadIdx.x;   // one per (d, ks, g): 128*8*4 = 4096
    if (i >= DD * 8 * 4) return;
    int g  = i & 3;
    int ks = (i >> 2) & 7;
    int d  = i >> 5;
    int dt = d >> 4, li = d & 15;
    const float* src = W1 + d * KD + ks * 32 + g * 8;
    float4 v0 = *(const float4*)(src);
    float4 v1 = *(const float4*)(src + 4);
    bf16x8 h = { (__bf16)v0.x, (__bf16)v0.y, (__bf16)v0.z, (__bf16)v0.w,
                 (__bf16)v1.x, (__bf16)v1.y, (__bf16)v1.z, (__bf16)v1.w };
    *(bf16x8*)&W1p[(size_t)(((dt * 8 + ks) * 64) + g * 16 + li) * 8] = h;
}

// Stage 1 (MFMA, 4 blocks/CU): one 32-row tile per block; x tile in LDS (17 KB);
// B-frags streamed from frag-major W1p (L2-hot, coalesced) with 1-step prefetch.
__global__ __launch_bounds__(256, 4) void stage1_kernel(
    const float* __restrict__ x, const __bf16* __restrict__ W1p,
    const float* __restrict__ b1, const float* __restrict__ W2,
    float* __restrict__ s, float* __restrict__ out, unsigned* __restrict__ counter)
{
    __shared__ __align__(16) __bf16 xs[ROWS * STR];   // 16896 B
    __shared__ float sred[4][ROWS];

    const int tid  = threadIdx.x;
    const int lane = tid & 63;
    const int w    = tid >> 6;
    const int g    = lane >> 4;
    const int li   = lane & 15;
    const int m0   = blockIdx.x * ROWS;

    if (blockIdx.x == 0 && tid == 0) { out[0] = 0.f; counter[0] = 0u; }

    // Issue x tile loads (coalesced float4; clamp rows: dup rows masked at the store)
    float4 xr[8];
    #pragma unroll
    for (int i = 0; i < 8; ++i) {
        int c = tid + i * 256;
        int r = c >> 6, kq = c & 63;
        int rr = m0 + r; rr = rr < NN ? rr : NN - 1;
        xr[i] = ((const float4*)x)[(size_t)rr * 64 + kq];
    }

    // Frag-major B bases: wave w owns d-tiles 2w, 2w+1. Prefetch ks=0.
    const __bf16* fb0 = W1p + ((size_t)((2 * w)     * 8) * 64 + lane) * 8;
    const __bf16* fb1 = W1p + ((size_t)((2 * w + 1) * 8) * 64 + lane) * 8;
    bf16x8 nb0 = *(const bf16x8*)(fb0);
    bf16x8 nb1 = *(const bf16x8*)(fb1);

    const int d0 = w * 32 + li;
    const float b1v0 = b1[d0], b1v1 = b1[d0 + 16];
    const float w2v0 = W2[d0], w2v1 = W2[d0 + 16];

    // Convert + stage x tile to LDS
    #pragma unroll
    for (int i = 0; i < 8; ++i) {
        int c = tid + i * 256;
        int r = c >> 6, kq = c & 63;
        bf16x4 h = { (__bf16)xr[i].x, (__bf16)xr[i].y, (__bf16)xr[i].z, (__bf16)xr[i].w };
        *(bf16x4*)&xs[r * STR + kq * 4] = h;
    }
    __syncthreads();

    // K-loop: A from LDS, B streamed (prefetch ks+1 under ks's MFMAs).
    // A and B both use k = ks*32 + g*8 + j for lane (g,li) — same bijection, so any HW k-order is fine.
    f32x4 acc[2][2] = {};
    #pragma unroll
    for (int ks = 0; ks < 8; ++ks) {
        bf16x8 cb0 = nb0, cb1 = nb1;
        if (ks < 7) {
            nb0 = *(const bf16x8*)(fb0 + (size_t)(ks + 1) * 64 * 8);
            nb1 = *(const bf16x8*)(fb1 + (size_t)(ks + 1) * 64 * 8);
        }
        const int ko = ks * 32 + g * 8;
        bf16x8 a0 = *(const bf16x8*)&xs[li * STR + ko];
        bf16x8 a1 = *(const bf16x8*)&xs[(li + 16) * STR + ko];
        acc[0][0] = __builtin_amdgcn_mfma_f32_16x16x32_bf16(a0, cb0, acc[0][0], 0, 0, 0);
        acc[0][1] = __builtin_amdgcn_mfma_f32_16x16x32_bf16(a0, cb1, acc[0][1], 0, 0, 0);
        acc[1][0] = __builtin_amdgcn_mfma_f32_16x16x32_bf16(a1, cb0, acc[1][0], 0, 0, 0);
        acc[1][1] = __builtin_amdgcn_mfma_f32_16x16x32_bf16(a1, cb1, acc[1][1], 0, 0, 0);
    }

    // Epilogue: v = sin(acc+b1)*W2, reduce over d (C/D: col=lane&15, row=(lane>>4)*4+reg)
    #pragma unroll
    for (int mt = 0; mt < 2; ++mt) {
        #pragma unroll
        for (int r = 0; r < 4; ++r) {
            float v = __sinf(acc[mt][0][r] + b1v0) * w2v0
                    + __sinf(acc[mt][1][r] + b1v1) * w2v1;
            v += __shfl_xor(v, 1); v += __shfl_xor(v, 2);
            v += __shfl_xor(v, 4); v += __shfl_xor(v, 8);
            if (li == 0) sred[w][mt * 16 + g * 4 + r] = v;
        }
    }
    __syncthreads();
    if (tid < ROWS) {
        int m = m0 + tid;
        if (m < NN) s[m] = sred[0][tid] + sred[1][tid] + sred[2][tid] + sred[3][tid];
    }
}

// Stage 2 (LDS-privatized, no device atomics): block (nr, ecid) scans chunk ecid,
// accumulates rows in its range into LDS, writes partial range to P[ecid][...].
__global__ __launch_bounds__(1024, 1) void spmv_lds_kernel(
    const int* __restrict__ erow, const int* __restrict__ ecol,
    const float* __restrict__ ew, const float* __restrict__ s,
    float* __restrict__ P)
{
    __shared__ float lt[RNG];
    const int tid  = threadIdx.x;
    const int ecid = blockIdx.x & 63;
    const int nr   = blockIdx.x >> 6;
    const int base = nr * RNG;

    for (int i = tid; i < RNG; i += 1024) lt[i] = 0.f;
    __syncthreads();

    const int4*   r4p = (const int4*)erow;
    const int4*   c4p = (const int4*)ecol;
    const float4* w4p = (const float4*)ew;
    for (int q = tid; q < QPC; q += 1024) {
        int i = ecid * QPC + q;
        int4   r4 = r4p[i];
        int4   c4 = c4p[i];
        float4 w4 = w4p[i];
        unsigned a;
        a = (unsigned)(r4.x - base); if (a < RNG) atomicAdd(&lt[a], w4.x * s[c4.x]);
        a = (unsigned)(r4.y - base); if (a < RNG) atomicAdd(&lt[a], w4.y * s[c4.y]);
        a = (unsigned)(r4.z - base); if (a < RNG) atomicAdd(&lt[a], w4.z * s[c4.z]);
        a = (unsigned)(r4.w - base); if (a < RNG) atomicAdd(&lt[a], w4.w * s[c4.w]);
    }
    __syncthreads();

    float4*       dst = (float4*)(P + (size_t)ecid * NN + base);
    const float4* src = (const float4*)lt;
    for (int j = tid; j < RNG / 4; j += 1024) dst[j] = src[j];
}

// Stage 3: out += sum_n sin(sum_ec P[ec][n] + b2)^2 ; last block applies sqrt.
__global__ void finish_lds_kernel(const float* __restrict__ P, const float* __restrict__ b2,
                                  float* __restrict__ out, unsigned* __restrict__ counter,
                                  int nblocks)
{
    int n = blockIdx.x * 256 + threadIdx.x;
    float v = 0.f;
    if (n < NN) {
        float a = 0.f;
        #pragma unroll 8
        for (int ec = 0; ec < EC; ++ec) a += P[(size_t)ec * NN + n];
        float o = __sinf(a + b2[0]);
        v = o * o;
    }
    #pragma unroll
    for (int off = 32; off; off >>= 1) v += __shfl_xor(v, off);
    __shared__ float partial[4];
    if ((threadIdx.x & 63) == 0) partial[threadIdx.x >> 6] = v;
    __syncthreads();
    if (threadIdx.x == 0) {
        atomicAdd(out, partial[0] + partial[1] + partial[2] + partial[3]);
        __threadfence();
        unsigned old = atomicAdd(counter, 1u);
        if (old == (unsigned)(nblocks - 1)) {
            float tot = atomicAdd(out, 0.f);   // atomic read: all prior adds visible
            out[0] = sqrtf(tot);
        }
    }
}

// ---- Fallback path (small workspace): dense atomic SpMV ----
__global__ void spmv_fallback_kernel(const int* __restrict__ erow, const int* __restrict__ ecol,
                                     const float* __restrict__ ew, const float* __restrict__ s,
                                     float* __restrict__ t)
{
    int i = blockIdx.x * 256 + threadIdx.x;
    if (i >= NE / 4) return;
    int4   r4 = ((const int4*)erow)[i];
    int4   c4 = ((const int4*)ecol)[i];
    float4 w4 = ((const float4*)ew)[i];
    atomicAdd(&t[r4.x], w4.x * s[c4.x]);
    atomicAdd(&t[r4.y], w4.y * s[c4.y]);
    atomicAdd(&t[r4.z], w4.z * s[c4.z]);
    atomicAdd(&t[r4.w], w4.w * s[c4.w]);
}

__global__ void finish_fallback_kernel(const float* __restrict__ t, const float* __restrict__ b2,
                                       float* __restrict__ out)
{
    int n = blockIdx.x * 256 + threadIdx.x;
    float v = 0.f;
    if (n < NN) { float o = __sinf(t[n] + b2[0]); v = o * o; }
    #pragma unroll
    for (int off = 32; off; off >>= 1) v += __shfl_xor(v, off);
    __shared__ float partial[4];
    if ((threadIdx.x & 63) == 0) partial[threadIdx.x >> 6] = v;
    __syncthreads();
    if (threadIdx.x == 0)
        atomicAdd(out, partial[0] + partial[1] + partial[2] + partial[3]);
}

__global__ void sqrt_kernel(float* out) { out[0] = sqrtf(out[0]); }

__global__ void zero_kernel(float* t, float* out)
{
    int i = blockIdx.x * 256 + threadIdx.x;
    if (i < NN) t[i] = 0.f;
    if (i == 0) out[0] = 0.f;
}

extern "C" void kernel_launch(void* const* d_in, const int* in_sizes, int n_in,
                              void* d_out, int out_size, void* d_ws, size_t ws_size,
                              hipStream_t stream)
{
    const float* x   = (const float*)d_in[0];
    const float* W1  = (const float*)d_in[1];
    const float* b1  = (const float*)d_in[2];
    const float* W2  = (const float*)d_in[3];
    const float* b2  = (const float*)d_in[4];
    const int*   er  = (const int*)d_in[5];
    const int*   ec  = ((const int*)d_in[5]) + NE;
    const float* ew  = (const float*)d_in[6];
    float* out = (float*)d_out;

    float*    ws    = (float*)d_ws;
    float*    s_buf = ws + S_OFF;
    float*    P     = ws + P_OFF;
    unsigned* cnt   = (unsigned*)(ws + CNT_OFF);
    __bf16*   W1p   = (__bf16*)(ws + W1P_OFF);

    if (ws_size >= WS_NEED) {
        prep_w1_kernel<<<16, 256, 0, stream>>>(W1, W1p);
        stage1_kernel<<<NT, 256, 0, stream>>>(x, W1p, b1, W2, s_buf, out, cnt);
        spmv_lds_kernel<<<NR * EC, 1024, 0, stream>>>(er, ec, ew, s_buf, P);
        int fb = (NN + 255) / 256;
        finish_lds_kernel<<<fb, 256, 0, stream>>>(P, b2, out, cnt, fb);
    } else {
        // Dense-atomic fallback (needs only ~400 KB of ws)
        __bf16*   W1pf = (__bf16*)(ws + 50176 + NN);
        unsigned* cntf = (unsigned*)(ws + 50176 + NN + DD * KD / 2);
        prep_w1_kernel<<<16, 256, 0, stream>>>(W1, W1pf);
        zero_kernel<<<(NN + 255) / 256, 256, 0, stream>>>(ws + 50176, out);
        stage1_kernel<<<NT, 256, 0, stream>>>(x, W1pf, b1, W2, s_buf, out, cntf);
        spmv_fallback_kernel<<<(NE / 4 + 255) / 256, 256, 0, stream>>>(er, ec, ew, s_buf, ws + 50176);
        finish_fallback_kernel<<<(NN + 255) / 256, 256, 0, stream>>>(ws + 50176, b2, out);
        sqrt_kernel<<<1, 1, 0, stream>>>(out);
    }
}